// Round 1
// baseline (518.871 us; speedup 1.0000x reference)
//
#include <hip/hip_runtime.h>

#define N_NODES 8192
#define N_EDGES 262144
#define FEAT    512
#define HIDDIM  512
#define NOUT    64

typedef short bf16x8 __attribute__((ext_vector_type(8)));
typedef float f32x4  __attribute__((ext_vector_type(4)));

__device__ __forceinline__ unsigned short f2bf(float f) {
  unsigned int u = __float_as_uint(f);
  u += 0x7fffu + ((u >> 16) & 1u);          // round-to-nearest-even
  return (unsigned short)(u >> 16);
}
__device__ __forceinline__ float bf2f(unsigned short h) {
  return __uint_as_float(((unsigned int)h) << 16);
}
__device__ __forceinline__ float lo2f(unsigned int v) { return __uint_as_float(v << 16); }
__device__ __forceinline__ float hi2f(unsigned int v) { return __uint_as_float(v & 0xffff0000u); }
__device__ __forceinline__ unsigned int packbf(float a, float b) {
  return (unsigned int)f2bf(a) | ((unsigned int)f2bf(b) << 16);
}

__device__ __forceinline__ void async_copy16(const unsigned short* g, unsigned short* l) {
  __builtin_amdgcn_global_load_lds(
      (const __attribute__((address_space(1))) unsigned int*)g,
      (__attribute__((address_space(3))) unsigned int*)l, 16, 0, 0);
}

// ---------------- casts ----------------
__global__ void cast4_k(const float* __restrict__ in, unsigned int* __restrict__ out, int n4) {
  int i = blockIdx.x * blockDim.x + threadIdx.x;
  if (i >= n4) return;
  float4 v = ((const float4*)in)[i];
  out[2 * i]     = packbf(v.x, v.y);
  out[2 * i + 1] = packbf(v.z, v.w);
}

// out[C][R] = bf16(in[R][C])  (R,C multiples of 32)
__global__ void tcast_k(const float* __restrict__ in, unsigned short* __restrict__ out, int R, int C) {
  __shared__ float tile[32][33];
  int bx = blockIdx.x * 32;  // col base in `in`
  int by = blockIdx.y * 32;  // row base in `in`
  int tx = threadIdx.x, ty = threadIdx.y;
#pragma unroll
  for (int j = 0; j < 32; j += 8)
    tile[ty + j][tx] = in[(size_t)(by + ty + j) * C + bx + tx];
  __syncthreads();
#pragma unroll
  for (int j = 0; j < 32; j += 8)
    out[(size_t)(bx + ty + j) * R + by + tx] = f2bf(tile[tx][ty + j]);
}

// ---------------- graph build ----------------
__global__ void init_k(int* __restrict__ deg, int* __restrict__ cursor) {
  int i = blockIdx.x * blockDim.x + threadIdx.x;
  if (i < N_NODES) { deg[i] = 1; cursor[i] = 0; }   // self-loop counts 1
}
__global__ void count_k(const int* __restrict__ dst, int* __restrict__ deg) {
  for (int i = blockIdx.x * blockDim.x + threadIdx.x; i < N_EDGES; i += gridDim.x * blockDim.x)
    atomicAdd(&deg[dst[i]], 1);
}
__global__ void dinv_k(const int* __restrict__ deg, float* __restrict__ dinv) {
  int i = blockIdx.x * blockDim.x + threadIdx.x;
  if (i < N_NODES) dinv[i] = rsqrtf((float)deg[i]);
}
// exclusive scan of (deg[i]-1) over 8192 entries, single block of 1024
__global__ __launch_bounds__(1024) void scan_k(const int* __restrict__ deg, int* __restrict__ offs) {
  __shared__ int sums[1024];
  int tid = threadIdx.x;
  int vals[8]; int s = 0;
#pragma unroll
  for (int k = 0; k < 8; k++) { vals[k] = deg[tid * 8 + k] - 1; s += vals[k]; }
  sums[tid] = s;
  __syncthreads();
  for (int off = 1; off < 1024; off <<= 1) {
    int add = (tid >= off) ? sums[tid - off] : 0;
    __syncthreads();
    sums[tid] += add;
    __syncthreads();
  }
  int prefix = (tid > 0) ? sums[tid - 1] : 0;
#pragma unroll
  for (int k = 0; k < 8; k++) { offs[tid * 8 + k] = prefix; prefix += vals[k]; }
  if (tid == 1023) offs[N_NODES] = prefix;
}
__global__ void scatter_k(const int* __restrict__ src, const int* __restrict__ dst,
                          const int* __restrict__ offs, int* __restrict__ cursor,
                          const float* __restrict__ dinv,
                          int* __restrict__ ssrc, float* __restrict__ enorm) {
  for (int i = blockIdx.x * blockDim.x + threadIdx.x; i < N_EDGES; i += gridDim.x * blockDim.x) {
    int s = src[i], d = dst[i];
    int pos = offs[d] + atomicAdd(&cursor[d], 1);
    ssrc[pos]  = s;
    enorm[pos] = dinv[s] * dinv[d];
  }
}

// ---------------- MFMA GEMM:  D[M][Ncols] = A[M][K] * B[Ncols][K]^T ----------------
template <bool OUT_BF16, bool ZERO_DIAG>
__global__ __launch_bounds__(256) void gemm_bt(
    const unsigned short* __restrict__ A, const unsigned short* __restrict__ B,
    void* __restrict__ Cout, int M, int Ncols, int K) {
  __shared__ unsigned short lA[128 * 32];
  __shared__ unsigned short lB[128 * 32];
  const int tid  = threadIdx.x;
  const int lane = tid & 63, w = tid >> 6;
  const int wm = w >> 1, wn = w & 1;
  const int lm = lane & 15, q = lane >> 4;
  const int bm = blockIdx.y * 128, bn = blockIdx.x * 128;

  f32x4 acc[4][4];
#pragma unroll
  for (int r = 0; r < 4; r++)
#pragma unroll
    for (int c = 0; c < 4; c++) acc[r][c] = (f32x4){0.f, 0.f, 0.f, 0.f};

  const int rowOff = tid >> 2;          // 0..63
  const int kOff   = (tid & 3) * 8;     // 0,8,16,24
  const unsigned short* gA0 = A + (size_t)(bm + rowOff) * K + kOff;
  const unsigned short* gA1 = gA0 + (size_t)64 * K;
  const unsigned short* gB0 = B + (size_t)(bn + rowOff) * K + kOff;
  const unsigned short* gB1 = gB0 + (size_t)64 * K;
  unsigned short* lAw = lA + w * 512;   // wave-uniform LDS base (lane*16B appended by HW)
  unsigned short* lBw = lB + w * 512;

  for (int k0 = 0; k0 < K; k0 += 32) {
    async_copy16(gA0 + k0, lAw);
    async_copy16(gA1 + k0, lAw + 2048);
    async_copy16(gB0 + k0, lBw);
    async_copy16(gB1 + k0, lBw + 2048);
    asm volatile("s_waitcnt vmcnt(0)" ::: "memory");
    __syncthreads();

    bf16x8 av[4], bv[4];
#pragma unroll
    for (int r = 0; r < 4; r++)
      av[r] = *(const bf16x8*)&lA[(wm * 64 + r * 16 + lm) * 32 + q * 8];
#pragma unroll
    for (int c = 0; c < 4; c++)
      bv[c] = *(const bf16x8*)&lB[(wn * 64 + c * 16 + lm) * 32 + q * 8];
#pragma unroll
    for (int r = 0; r < 4; r++)
#pragma unroll
      for (int c = 0; c < 4; c++)
        acc[r][c] = __builtin_amdgcn_mfma_f32_16x16x32_bf16(av[r], bv[c], acc[r][c], 0, 0, 0);
    __syncthreads();
  }

  const int grow0 = bm + wm * 64 + q * 4;
  const int gcol0 = bn + wn * 64 + lm;
#pragma unroll
  for (int r = 0; r < 4; r++) {
#pragma unroll
    for (int c = 0; c < 4; c++) {
      int col = gcol0 + c * 16;
#pragma unroll
      for (int v = 0; v < 4; v++) {
        int row = grow0 + r * 16 + v;
        float val = acc[r][c][v];
        if (ZERO_DIAG && row == col) val = 0.f;
        if (OUT_BF16)
          ((unsigned short*)Cout)[(size_t)row * Ncols + col] = f2bf(val);
        else
          ((float*)Cout)[(size_t)row * Ncols + col] = val;
      }
    }
  }
}

// ---------------- aggregation: out[i] = relu( sum_e norm*h[src] + dinv_i^2*h[i] + b ) ----------------
template <bool NORM>
__global__ __launch_bounds__(256) void aggregate_k(
    const unsigned int* __restrict__ Hu,      // [N][256] uint = 512 bf16
    const int* __restrict__ offs, const int* __restrict__ ssrc,
    const float* __restrict__ enorm, const float* __restrict__ dinv,
    const float* __restrict__ bias,
    unsigned int* __restrict__ outU, unsigned int* __restrict__ yU) {
  const int i = blockIdx.x;
  const int tid = threadIdx.x;
  __shared__ int   sS[256];
  __shared__ float sN[256];
  __shared__ float wsum[4];

  float di = dinv[i];
  unsigned int hv = Hu[(size_t)i * 256 + tid];
  float ax = lo2f(hv) * di * di;
  float ay = hi2f(hv) * di * di;

  int e0 = offs[i], e1 = offs[i + 1];
  for (int base = e0; base < e1; base += 256) {
    int n = min(256, e1 - base);
    if (tid < n) { sS[tid] = ssrc[base + tid]; sN[tid] = enorm[base + tid]; }
    __syncthreads();
    int j = 0;
    for (; j + 4 <= n; j += 4) {
      int s0 = sS[j], s1 = sS[j + 1], s2 = sS[j + 2], s3 = sS[j + 3];
      float n0 = sN[j], n1 = sN[j + 1], n2 = sN[j + 2], n3 = sN[j + 3];
      unsigned int v0 = Hu[(size_t)s0 * 256 + tid];
      unsigned int v1 = Hu[(size_t)s1 * 256 + tid];
      unsigned int v2 = Hu[(size_t)s2 * 256 + tid];
      unsigned int v3 = Hu[(size_t)s3 * 256 + tid];
      ax = fmaf(n0, lo2f(v0), ax); ay = fmaf(n0, hi2f(v0), ay);
      ax = fmaf(n1, lo2f(v1), ax); ay = fmaf(n1, hi2f(v1), ay);
      ax = fmaf(n2, lo2f(v2), ax); ay = fmaf(n2, hi2f(v2), ay);
      ax = fmaf(n3, lo2f(v3), ax); ay = fmaf(n3, hi2f(v3), ay);
    }
    for (; j < n; j++) {
      int s = sS[j]; float nw = sN[j];
      unsigned int v = Hu[(size_t)s * 256 + tid];
      ax = fmaf(nw, lo2f(v), ax); ay = fmaf(nw, hi2f(v), ay);
    }
    __syncthreads();
  }

  float rx = fmaxf(ax + bias[tid * 2],     0.f);
  float ry = fmaxf(ay + bias[tid * 2 + 1], 0.f);
  outU[(size_t)i * 256 + tid] = packbf(rx, ry);

  if (NORM) {
    float ss = rx * rx + ry * ry;
    for (int o = 32; o > 0; o >>= 1) ss += __shfl_down(ss, o);
    if ((tid & 63) == 0) wsum[tid >> 6] = ss;
    __syncthreads();
    float tot = wsum[0] + wsum[1] + wsum[2] + wsum[3];
    float rn = tot > 0.f ? 1.f / sqrtf(tot) : 0.f;
    yU[(size_t)i * 256 + tid] = packbf(rx * rn, ry * rn);
  }
}

// ---------------- logits: out[N][64] = x_hid @ fcW + fcb ----------------
__global__ __launch_bounds__(256) void logits_k(
    const unsigned short* __restrict__ xh,  // [N][512] bf16
    const unsigned short* __restrict__ fw,  // [512][64] bf16 (original layout)
    const float* __restrict__ fcb, float* __restrict__ out) {
  __shared__ unsigned short sX[512 * 4];    // transposed [k][r]
  int tid = threadIdx.x;
  int rowBase = blockIdx.x * 4;
  for (int idx = tid; idx < 2048; idx += 256) {
    int r = idx >> 9, k = idx & 511;
    sX[k * 4 + r] = xh[(size_t)(rowBase + r) * 512 + k];
  }
  __syncthreads();
  int c = tid & 63, r = tid >> 6;
  float acc = 0.f;
#pragma unroll 8
  for (int k = 0; k < 512; k++)
    acc = fmaf(bf2f(sX[k * 4 + r]), bf2f(fw[(size_t)k * 64 + c]), acc);
  out[(size_t)(rowBase + r) * 64 + c] = acc + fcb[c];
}

extern "C" void kernel_launch(void* const* d_in, const int* in_sizes, int n_in,
                              void* d_out, int out_size, void* d_ws, size_t ws_size,
                              hipStream_t stream) {
  const float* x   = (const float*)d_in[0];
  const int*   ei  = (const int*)d_in[1];
  const float* W1  = (const float*)d_in[2];
  const float* b1  = (const float*)d_in[3];
  const float* W2  = (const float*)d_in[4];
  const float* b2  = (const float*)d_in[5];
  const float* fcW = (const float*)d_in[6];
  const float* fcb = (const float*)d_in[7];
  const int* src = ei;
  const int* dst = ei + N_EDGES;

  float* logits = (float*)d_out;
  float* xdis   = logits + (size_t)N_NODES * NOUT;

  char* p = (char*)d_ws;
  auto alloc = [&](size_t bytes) { char* r = p; p += (bytes + 255) & ~(size_t)255; return r; };
  unsigned short* xb   = (unsigned short*)alloc((size_t)N_NODES * FEAT * 2);
  unsigned short* hb   = (unsigned short*)alloc((size_t)N_NODES * HIDDIM * 2);
  unsigned short* h1b  = (unsigned short*)alloc((size_t)N_NODES * HIDDIM * 2);
  unsigned short* xhb  = (unsigned short*)alloc((size_t)N_NODES * HIDDIM * 2);
  unsigned short* yb   = (unsigned short*)alloc((size_t)N_NODES * HIDDIM * 2);
  unsigned short* w1t  = (unsigned short*)alloc((size_t)FEAT * HIDDIM * 2);
  unsigned short* w2t  = (unsigned short*)alloc((size_t)HIDDIM * HIDDIM * 2);
  unsigned short* fwb  = (unsigned short*)alloc((size_t)HIDDIM * NOUT * 2);
  int*   deg    = (int*)alloc(N_NODES * 4);
  float* dinv   = (float*)alloc(N_NODES * 4);
  int*   offs   = (int*)alloc((N_NODES + 1) * 4);
  int*   cursor = (int*)alloc(N_NODES * 4);
  int*   ssrc   = (int*)alloc(N_EDGES * 4);
  float* enorm  = (float*)alloc(N_EDGES * 4);

  // casts (bf16)
  cast4_k<<<(N_NODES * FEAT / 4 + 255) / 256, 256, 0, stream>>>(x, (unsigned int*)xb, N_NODES * FEAT / 4);
  tcast_k<<<dim3(HIDDIM / 32, FEAT / 32), dim3(32, 8), 0, stream>>>(W1, w1t, FEAT, HIDDIM);
  tcast_k<<<dim3(HIDDIM / 32, HIDDIM / 32), dim3(32, 8), 0, stream>>>(W2, w2t, HIDDIM, HIDDIM);
  cast4_k<<<(HIDDIM * NOUT / 4 + 255) / 256, 256, 0, stream>>>(fcW, (unsigned int*)fwb, HIDDIM * NOUT / 4);

  // graph build (CSR by dst)
  init_k<<<N_NODES / 256, 256, 0, stream>>>(deg, cursor);
  count_k<<<256, 256, 0, stream>>>(dst, deg);
  dinv_k<<<N_NODES / 256, 256, 0, stream>>>(deg, dinv);
  scan_k<<<1, 1024, 0, stream>>>(deg, offs);
  scatter_k<<<256, 256, 0, stream>>>(src, dst, offs, cursor, dinv, ssrc, enorm);

  // conv1: h = x @ W1 ; h1 = relu(agg(h) + b1)
  gemm_bt<true, false><<<dim3(HIDDIM / 128, N_NODES / 128), 256, 0, stream>>>(xb, w1t, hb, N_NODES, HIDDIM, FEAT);
  aggregate_k<false><<<N_NODES, 256, 0, stream>>>((const unsigned int*)hb, offs, ssrc, enorm, dinv, b1,
                                                  (unsigned int*)h1b, nullptr);
  // conv2: h2 = h1 @ W2 ; x_hid = relu(agg(h2) + b2), y = normalize(x_hid)
  gemm_bt<true, false><<<dim3(HIDDIM / 128, N_NODES / 128), 256, 0, stream>>>(h1b, w2t, hb, N_NODES, HIDDIM, HIDDIM);
  aggregate_k<true><<<N_NODES, 256, 0, stream>>>((const unsigned int*)hb, offs, ssrc, enorm, dinv, b2,
                                                 (unsigned int*)xhb, (unsigned int*)yb);

  // logits
  logits_k<<<N_NODES / 4, 256, 0, stream>>>(xhb, fwb, fcb, logits);

  // x_dis = y @ y^T with zero diagonal
  gemm_bt<false, true><<<dim3(N_NODES / 128, N_NODES / 128), 256, 0, stream>>>(yb, yb, xdis, N_NODES, N_NODES, HIDDIM);
}